// Round 14
// baseline (176.003 us; speedup 1.0000x reference)
//
#include <hip/hip_runtime.h>
#include <hip/hip_bf16.h>

#define N_NODES 50000
#define E_EDGES 1600000
#define E_TOT   (E_EDGES + N_NODES)   // 1,650,000
#define NEG_SLOPE 0.2f

#define NB       196                  // buckets of 256 dst nodes
#define S1_TILE  4096
#define NT       ((E_TOT + S1_TILE - 1) / S1_TILE)   // 403 tiles
#define S2_CAP   10240
#define GB1      ((N_NODES + 127) / 128)             // 391 gemm tiles

typedef _Float16 h2 __attribute__((ext_vector_type(2)));
typedef _Float16 h4 __attribute__((ext_vector_type(4)));
typedef _Float16 h8 __attribute__((ext_vector_type(8)));

__device__ __forceinline__ float fdot2h(h2 a, h2 b, float c)
{
#if __has_builtin(__builtin_amdgcn_fdot2)
    return __builtin_amdgcn_fdot2(a, b, c, false);
#else
    return c + (float)a[0] * (float)b[0] + (float)a[1] * (float)b[1];
#endif
}

__device__ __forceinline__ h2 habs2(h2 e)
{
    unsigned int u = __builtin_bit_cast(unsigned int, e) & 0x7FFF7FFFu;
    return __builtin_bit_cast(h2, u);
}

// inclusive wave scan (64 lanes)
__device__ __forceinline__ int wave_iscan(int v, int lane)
{
#pragma unroll
    for (int off = 1; off < 64; off <<= 1) {
        int u = __shfl_up(v, off);
        if (lane >= off) v += u;
    }
    return v;
}

// ---------------------------------------------------------------------------
// Fused: layer-1 transform (blocks 0..2*GB1) + tile_hist (blocks 2*GB1..).
// ---------------------------------------------------------------------------
__global__ __launch_bounds__(256) void fused_t1_hist(
    const float* __restrict__ x,
    const float* __restrict__ Wl, const float* __restrict__ Wr,
    _Float16* __restrict__ xl, _Float16* __restrict__ xr,
    const int* __restrict__ src, const int* __restrict__ dst,
    int* __restrict__ counts, int* __restrict__ done)
{
    __shared__ h2 xs2[16][128];
    __shared__ h2 ws2[16][128];
    __shared__ int hh[NB];
    const int t = threadIdx.x;

    if (blockIdx.x >= 2 * GB1) {
        // ---- tile_hist part ----
        const int tile = blockIdx.x - 2 * GB1;
        if (tile == 0 && t == 0) *done = 0;    // reset for row_scan_base
        const int base = tile * S1_TILE;
        for (int i = t; i < NB; i += 256) hh[i] = 0;
        __syncthreads();
#pragma unroll
        for (int k = 0; k < S1_TILE / 256; ++k) {
            const int i = base + k * 256 + t;
            if (i < E_TOT) {
                const int d = (i < E_EDGES) ? dst[i] : (i - E_EDGES);
                atomicAdd(&hh[d >> 8], 1);
            }
        }
        __syncthreads();
        for (int b = t; b < NB; b += 256)
            counts[tile * NB + b] = hh[b];
        return;
    }

    // ---- transform1 part ----
    const int n0 = (blockIdx.x >> 1) * 128;
    const float* __restrict__ W = (blockIdx.x & 1) ? Wr : Wl;
    _Float16* __restrict__ Y = (blockIdx.x & 1) ? xr : xl;
    const int tc = t & 15;
    const int tn = t >> 4;

    float acc[2][4][2][4];
#pragma unroll
    for (int nh = 0; nh < 2; ++nh)
#pragma unroll
        for (int i = 0; i < 4; ++i)
#pragma unroll
            for (int ch = 0; ch < 2; ++ch)
#pragma unroll
                for (int j = 0; j < 4; ++j) acc[nh][i][ch][j] = 0.f;

    for (int k0 = 0; k0 < 128; k0 += 32) {
        {
            const int node = t >> 1;
            const int kh = (t & 1) * 16;
            const int gn = n0 + node;
#pragma unroll
            for (int q = 0; q < 4; ++q) {
                float4 v = make_float4(0.f, 0.f, 0.f, 0.f);
                if (gn < N_NODES)
                    v = *(const float4*)&x[(size_t)gn * 128 + k0 + kh + q * 4];
                h2 p0 = {(_Float16)v.x, (_Float16)v.y};
                h2 p1 = {(_Float16)v.z, (_Float16)v.w};
                xs2[kh / 2 + q * 2 + 0][node] = p0;
                xs2[kh / 2 + q * 2 + 1][node] = p1;
            }
        }
        {
            const int c = t & 127;
            const int kq = (t >> 7) * 16;
#pragma unroll
            for (int ii = 0; ii < 8; ++ii) {
                h2 pw = {(_Float16)W[(size_t)(k0 + kq + 2 * ii) * 128 + c],
                         (_Float16)W[(size_t)(k0 + kq + 2 * ii + 1) * 128 + c]};
                ws2[kq / 2 + ii][c] = pw;
            }
        }
        __syncthreads();
#pragma unroll 4
        for (int k2 = 0; k2 < 16; ++k2) {
            h2 a0[4], a1[4], b0[4], b1[4];
#pragma unroll
            for (int j = 0; j < 4; ++j) {
                a0[j] = xs2[k2][tn * 4 + j];
                a1[j] = xs2[k2][64 + tn * 4 + j];
                b0[j] = ws2[k2][tc * 4 + j];
                b1[j] = ws2[k2][64 + tc * 4 + j];
            }
#pragma unroll
            for (int i = 0; i < 4; ++i)
#pragma unroll
                for (int j = 0; j < 4; ++j) {
                    acc[0][i][0][j] = fdot2h(a0[i], b0[j], acc[0][i][0][j]);
                    acc[0][i][1][j] = fdot2h(a0[i], b1[j], acc[0][i][1][j]);
                    acc[1][i][0][j] = fdot2h(a1[i], b0[j], acc[1][i][0][j]);
                    acc[1][i][1][j] = fdot2h(a1[i], b1[j], acc[1][i][1][j]);
                }
        }
        __syncthreads();
    }
#pragma unroll
    for (int nh = 0; nh < 2; ++nh)
#pragma unroll
        for (int i = 0; i < 4; ++i) {
            const int node = n0 + nh * 64 + tn * 4 + i;
            if (node < N_NODES) {
#pragma unroll
                for (int ch = 0; ch < 2; ++ch) {
                    h4 v;
                    v[0] = (_Float16)acc[nh][i][ch][0];
                    v[1] = (_Float16)acc[nh][i][ch][1];
                    v[2] = (_Float16)acc[nh][i][ch][2];
                    v[3] = (_Float16)acc[nh][i][ch][3];
                    *(h4*)&Y[(size_t)node * 128 + ch * 64 + tc * 4] = v;
                }
            }
        }
}

// ---------------------------------------------------------------------------
// Layer-2 transform: [N,128] fp16 @ (Wl2|Wr2)[128,32] -> hl, hr fp16.
// ---------------------------------------------------------------------------
__global__ __launch_bounds__(256) void transform2_gemm(
    const _Float16* __restrict__ h,
    const float* __restrict__ Wl, const float* __restrict__ Wr,
    _Float16* __restrict__ hl, _Float16* __restrict__ hr)
{
    __shared__ h2 xs2[16][128];
    __shared__ h2 ws2[16][64];
    const int n0 = blockIdx.x * 128;
    const int t = threadIdx.x;
    const int tc = t & 15;
    const int tn = t >> 4;

    float acc[2][4][4];
#pragma unroll
    for (int nh = 0; nh < 2; ++nh)
#pragma unroll
        for (int i = 0; i < 4; ++i)
#pragma unroll
            for (int j = 0; j < 4; ++j) acc[nh][i][j] = 0.f;

    for (int k0 = 0; k0 < 128; k0 += 32) {
        {
            const int node = t >> 1;
            const int kh = (t & 1) * 16;
            const int gn = n0 + node;
            h8 v0 = {}, v1 = {};
            if (gn < N_NODES) {
                v0 = *(const h8*)&h[(size_t)gn * 128 + k0 + kh];
                v1 = *(const h8*)&h[(size_t)gn * 128 + k0 + kh + 8];
            }
#pragma unroll
            for (int q = 0; q < 4; ++q) {
                h2 p0 = {v0[2 * q], v0[2 * q + 1]};
                h2 p1 = {v1[2 * q], v1[2 * q + 1]};
                xs2[kh / 2 + q][node] = p0;
                xs2[kh / 2 + 4 + q][node] = p1;
            }
        }
        {
            const int c = t & 63;
            const int kq = (t >> 6) * 8;
            const float* __restrict__ Wm = (c < 32) ? Wl : Wr;
            const int wc = c & 31;
#pragma unroll
            for (int ii = 0; ii < 4; ++ii) {
                h2 pw = {(_Float16)Wm[(size_t)(k0 + kq + 2 * ii) * 32 + wc],
                         (_Float16)Wm[(size_t)(k0 + kq + 2 * ii + 1) * 32 + wc]};
                ws2[kq / 2 + ii][c] = pw;
            }
        }
        __syncthreads();
#pragma unroll 4
        for (int k2 = 0; k2 < 16; ++k2) {
            h2 a0[4], a1[4], b[4];
#pragma unroll
            for (int j = 0; j < 4; ++j) {
                a0[j] = xs2[k2][tn * 4 + j];
                a1[j] = xs2[k2][64 + tn * 4 + j];
                b[j] = ws2[k2][tc * 4 + j];
            }
#pragma unroll
            for (int i = 0; i < 4; ++i)
#pragma unroll
                for (int j = 0; j < 4; ++j) {
                    acc[0][i][j] = fdot2h(a0[i], b[j], acc[0][i][j]);
                    acc[1][i][j] = fdot2h(a1[i], b[j], acc[1][i][j]);
                }
        }
        __syncthreads();
    }
    _Float16* __restrict__ Y = (tc < 8) ? hl : hr;
    const int col = (tc < 8) ? tc * 4 : tc * 4 - 32;
#pragma unroll
    for (int nh = 0; nh < 2; ++nh)
#pragma unroll
        for (int i = 0; i < 4; ++i) {
            const int node = n0 + nh * 64 + tn * 4 + i;
            if (node < N_NODES) {
                h4 v;
                v[0] = (_Float16)acc[nh][i][0];
                v[1] = (_Float16)acc[nh][i][1];
                v[2] = (_Float16)acc[nh][i][2];
                v[3] = (_Float16)acc[nh][i][3];
                *(h4*)&Y[(size_t)node * 32 + col] = v;
            }
        }
}

// ---------------------------------------------------------------------------
// row_scan + folded bucket_base (last-block-done pattern).
// ---------------------------------------------------------------------------
__global__ __launch_bounds__(512) void row_scan_base(
    const int* __restrict__ counts, int* __restrict__ rstart,
    int* __restrict__ bcount, int* __restrict__ bbase, int* __restrict__ done)
{
    __shared__ int wsum[8];
    __shared__ int amLast;
    const int b = blockIdx.x;
    const int t = threadIdx.x;
    const int lane = t & 63, wid = t >> 6;
    const int v = (t < NT) ? counts[t * NB + b] : 0;
    int inc = wave_iscan(v, lane);
    if (lane == 63) wsum[wid] = inc;
    __syncthreads();
    if (t == 0) {
        int s = 0;
#pragma unroll
        for (int w = 0; w < 8; ++w) { int u = wsum[w]; wsum[w] = s; s += u; }
    }
    __syncthreads();
    const int excl = inc - v + wsum[wid];
    if (t < NT) rstart[b * NT + t] = excl;
    if (t == 511) {
        bcount[b] = excl;   // v==0 here, excl == row total
        __threadfence();
        const int old = atomicAdd(done, 1);
        amLast = (old == NB - 1) ? 1 : 0;
    }
    __syncthreads();
    if (amLast) {
        __threadfence();    // see all blocks' bcount
        const int v2 = (t < NB) ? bcount[t] : 0;
        int inc2 = wave_iscan(v2, lane);
        if (lane == 63 && wid < 4) wsum[wid] = inc2;
        __syncthreads();
        if (t == 0) {
            int s = 0;
#pragma unroll
            for (int w = 0; w < 4; ++w) { int u = wsum[w]; wsum[w] = s; s += u; }
        }
        __syncthreads();
        if (t < 256) {
            const int excl2 = inc2 - v2 + wsum[wid];
            if (t < NB) bbase[t] = excl2;
            if (t == NB - 1) bbase[NB] = excl2 + v2;   // == E_TOT
        }
    }
}

// tile_scatter: hist comes from the counts row (already computed in stage 1)
// instead of re-histing with LDS atomics.
__global__ __launch_bounds__(512) void tile_scatter(
    const int* __restrict__ src, const int* __restrict__ dst,
    const int* __restrict__ counts,
    const int* __restrict__ rstart, const int* __restrict__ bbase,
    unsigned int* __restrict__ bucket_data)
{
    __shared__ int cur[NB];
    __shared__ int rs[NB];
    __shared__ int wsum[8];
    __shared__ unsigned int srt[S1_TILE];   // 16 KB
    const int t = threadIdx.x;
    const int tile = blockIdx.x;
    const int base = tile * S1_TILE;
    const int tcount = min(S1_TILE, E_TOT - base);

    // read edges into registers (single pass)
    int eb[S1_TILE / 512];
    unsigned int ee[S1_TILE / 512];
#pragma unroll
    for (int k = 0; k < S1_TILE / 512; ++k) {
        const int i = base + k * 512 + t;
        eb[k] = -1;
        if (i < E_TOT) {
            int s, d;
            if (i < E_EDGES) { s = src[i]; d = dst[i]; }
            else { s = i - E_EDGES; d = s; }     // self loop
            const int b = d >> 8;
            eb[k] = b;
            ee[k] = ((unsigned)b << 24) | ((unsigned)(d & 255) << 16) | (unsigned)s;
        }
    }
    // scan the precomputed histogram row
    {
        const int lane = t & 63, wid = t >> 6;
        const int v = (t < NB) ? counts[tile * NB + t] : 0;
        int inc = wave_iscan(v, lane);
        if (lane == 63 && wid < 4) wsum[wid] = inc;
        __syncthreads();
        if (t == 0) {
            int s = 0;
#pragma unroll
            for (int w = 0; w < 4; ++w) { int u = wsum[w]; wsum[w] = s; s += u; }
        }
        __syncthreads();
        if (t < NB) {
            const int excl = inc - v + wsum[wid];
            cur[t] = excl;
            rs[t] = bbase[t] + rstart[t * NT + tile] - excl;
        }
    }
    __syncthreads();
#pragma unroll
    for (int k = 0; k < S1_TILE / 512; ++k) {
        if (eb[k] >= 0) {
            const int pos = atomicAdd(&cur[eb[k]], 1);
            srt[pos] = ee[k];
        }
    }
    __syncthreads();
    for (int i = t; i < tcount; i += 512) {
        const unsigned int e = srt[i];
        bucket_data[rs[e >> 24] + i] = e;
    }
}

// Two-pass in-bucket sort (src-coarse then dst-byte), LDS-staged output.
__global__ __launch_bounds__(1024) void bucket_sort(
    const unsigned int* __restrict__ bucket_data,
    const int* __restrict__ bbase,
    int* __restrict__ offs, unsigned short* __restrict__ sorted_src)
{
    __shared__ int hist[256];                   // dst-byte histogram
    __shared__ int hsrc[256];                   // src-high histogram
    __shared__ int cur[256];
    __shared__ int csrc[256];
    __shared__ int wsum[4];
    __shared__ unsigned int srt4[S2_CAP];       // 40 KB
    __shared__ unsigned short srt2[S2_CAP];     // 20 KB
    const int b = blockIdx.x;
    const int t = threadIdx.x;
    const int lo = bbase[b], hi = bbase[b + 1];
    const int c = hi - lo;
    if (t < 256) { hist[t] = 0; hsrc[t] = 0; }
    __syncthreads();
    for (int i = t; i < c; i += 1024) {
        const unsigned int e = bucket_data[lo + i];
        atomicAdd(&hist[(e >> 16) & 255u], 1);
        atomicAdd(&hsrc[(e >> 8) & 255u], 1);
    }
    __syncthreads();
    // scan hsrc -> csrc
    {
        const int lane = t & 63, wid = t >> 6;
        const int v = (t < 256) ? hsrc[t] : 0;
        int inc = wave_iscan(v, lane);
        if (lane == 63 && wid < 4) wsum[wid] = inc;
        __syncthreads();
        if (t == 0) {
            int s = 0;
#pragma unroll
            for (int w = 0; w < 4; ++w) { int u = wsum[w]; wsum[w] = s; s += u; }
        }
        __syncthreads();
        if (t < 256) csrc[t] = inc - v + wsum[wid];
        __syncthreads();
    }
    // scan hist -> cur (+offs)
    {
        const int lane = t & 63, wid = t >> 6;
        const int v = (t < 256) ? hist[t] : 0;
        int inc = wave_iscan(v, lane);
        if (lane == 63 && wid < 4) wsum[wid] = inc;
        __syncthreads();
        if (t == 0) {
            int s = 0;
#pragma unroll
            for (int w = 0; w < 4; ++w) { int u = wsum[w]; wsum[w] = s; s += u; }
        }
        __syncthreads();
        if (t < 256) {
            const int excl = inc - v + wsum[wid];
            cur[t] = excl;
            const int node = b * 256 + t;
            if (node < N_NODES) offs[node] = lo + excl;
        }
    }
    if (b == 0 && t == 0) offs[N_NODES] = E_TOT;
    __syncthreads();
    // pass 1: scatter by src-high into srt4
    for (int i = t; i < c; i += 1024) {
        const unsigned int e = bucket_data[lo + i];
        const int pos = atomicAdd(&csrc[(e >> 8) & 255u], 1);
        srt4[pos] = e;
    }
    __syncthreads();
    // pass 2: scatter by dst-byte (approx stable) into srt2
    for (int i = t; i < c; i += 1024) {
        const unsigned int e = srt4[i];
        const int pos = atomicAdd(&cur[(e >> 16) & 255u], 1);
        srt2[pos] = (unsigned short)(e & 0xFFFFu);
    }
    __syncthreads();
    for (int i = t; i < c; i += 1024)
        sorted_src[lo + i] = srt2[i];           // coalesced 2B stores
}

// ---------------------------------------------------------------------------
// Fused GATv2 edge pass, fp16, quad-unrolled online softmax, SPLIT-PAIR,
// with index-only prefetch (next quad's 4 indices loaded before compute).
// ---------------------------------------------------------------------------
template <int C, int LPG, typename OUT_T>
__global__ __launch_bounds__(256) void gat_edge_pass(
    const _Float16* __restrict__ xl, const _Float16* __restrict__ xr,
    const float* __restrict__ att, const float* __restrict__ bias,
    const int* __restrict__ offs, const unsigned short* __restrict__ ssrc,
    OUT_T* __restrict__ out)
{
    constexpr int GPN = 2 * LPG;       // lanes per node (two half-groups)
    static_assert(C == LPG * 8, "8 halves per lane per half-group");
    const int node = (blockIdx.x * 256 + threadIdx.x) / GPN;
    if (node >= N_NODES) return;
    const int half = (threadIdx.x / LPG) & 1;
    const int lane = threadIdx.x % LPG;
    const int cb = lane * 8;

    h2 a6[4], a4[4], r2[4];
    {
        const h8 rv = *(const h8*)(xr + (size_t)node * C + cb);
#pragma unroll
        for (int i = 0; i < 4; ++i) {
            const float av0 = att[cb + 2 * i], av1 = att[cb + 2 * i + 1];
            h2 t6 = {(_Float16)(0.6f * av0), (_Float16)(0.6f * av1)};
            h2 t4 = {(_Float16)(0.4f * av0), (_Float16)(0.4f * av1)};
            a6[i] = t6; a4[i] = t4;
            h2 rr = {rv[2 * i], rv[2 * i + 1]};
            r2[i] = rr;
        }
    }
    float acc[8];
#pragma unroll
    for (int v = 0; v < 8; ++v) acc[v] = 0.f;
    float m = -3.0e38f, denom = 0.f;

    const int p0 = offs[node];
    const int pE = offs[node + 1];
    const int hlen = (pE - p0 + 1) >> 1;
    int p = half ? (p0 + hlen) : p0;
    const int p1 = half ? pE : (p0 + hlen);

    int q0 = 0, q1 = 0, q2 = 0, q3 = 0;
    if (p + 4 <= p1) {
        q0 = ssrc[p]; q1 = ssrc[p + 1]; q2 = ssrc[p + 2]; q3 = ssrc[p + 3];
    }
    while (p + 4 <= p1) {
        const int pn = p + 4;
        int n0 = 0, n1 = 0, n2 = 0, n3 = 0;
        if (pn + 4 <= p1) {      // prefetch next quad's indices
            n0 = ssrc[pn]; n1 = ssrc[pn + 1]; n2 = ssrc[pn + 2]; n3 = ssrc[pn + 3];
        }
        const h8 x0 = *(const h8*)(xl + (size_t)q0 * C + cb);
        const h8 x1 = *(const h8*)(xl + (size_t)q1 * C + cb);
        const h8 x2 = *(const h8*)(xl + (size_t)q2 * C + cb);
        const h8 x3 = *(const h8*)(xl + (size_t)q3 * C + cb);
        float d0 = 0.f, d1 = 0.f, d2 = 0.f, d3 = 0.f;
#pragma unroll
        for (int i = 0; i < 4; ++i) {
            h2 xa = {x0[2 * i], x0[2 * i + 1]};
            h2 xb = {x1[2 * i], x1[2 * i + 1]};
            h2 xc = {x2[2 * i], x2[2 * i + 1]};
            h2 xd = {x3[2 * i], x3[2 * i + 1]};
            h2 e0 = xa + r2[i], e1 = xb + r2[i];
            h2 e2 = xc + r2[i], e3 = xd + r2[i];
            d0 = fdot2h(a6[i], e0, fdot2h(a4[i], habs2(e0), d0));
            d1 = fdot2h(a6[i], e1, fdot2h(a4[i], habs2(e1), d1));
            d2 = fdot2h(a6[i], e2, fdot2h(a4[i], habs2(e2), d2));
            d3 = fdot2h(a6[i], e3, fdot2h(a4[i], habs2(e3), d3));
        }
#pragma unroll
        for (int off = LPG >> 1; off; off >>= 1) {
            d0 += __shfl_xor(d0, off);
            d1 += __shfl_xor(d1, off);
            d2 += __shfl_xor(d2, off);
            d3 += __shfl_xor(d3, off);
        }
        const float pm = fmaxf(fmaxf(d0, d1), fmaxf(d2, d3));
        if (__builtin_expect(pm > m + 8.f, 0)) {
            const float sc = __expf(m - pm);     // first quad: exp(-inf) = 0
            m = pm;
            denom *= sc;
#pragma unroll
            for (int v = 0; v < 8; ++v) acc[v] *= sc;
        }
        const float w0 = __expf(d0 - m), w1 = __expf(d1 - m);
        const float w2 = __expf(d2 - m), w3 = __expf(d3 - m);
        denom += (w0 + w1) + (w2 + w3);
        const h2 wA = {(_Float16)w0, (_Float16)w1};
        const h2 wB = {(_Float16)w2, (_Float16)w3};
#pragma unroll
        for (int v = 0; v < 8; ++v) {
            h2 pA = {x0[v], x1[v]};
            h2 pB = {x2[v], x3[v]};
            acc[v] = fdot2h(wA, pA, fdot2h(wB, pB, acc[v]));
        }
        q0 = n0; q1 = n1; q2 = n2; q3 = n3;
        p = pn;
    }
    for (; p + 2 <= p1; p += 2) {
        const int s0 = ssrc[p], s1 = ssrc[p + 1];
        const h8 x0 = *(const h8*)(xl + (size_t)s0 * C + cb);
        const h8 x1 = *(const h8*)(xl + (size_t)s1 * C + cb);
        float d0 = 0.f, d1 = 0.f;
#pragma unroll
        for (int i = 0; i < 4; ++i) {
            h2 xa = {x0[2 * i], x0[2 * i + 1]};
            h2 xb = {x1[2 * i], x1[2 * i + 1]};
            h2 e0 = xa + r2[i], e1 = xb + r2[i];
            d0 = fdot2h(a6[i], e0, fdot2h(a4[i], habs2(e0), d0));
            d1 = fdot2h(a6[i], e1, fdot2h(a4[i], habs2(e1), d1));
        }
#pragma unroll
        for (int off = LPG >> 1; off; off >>= 1) {
            d0 += __shfl_xor(d0, off);
            d1 += __shfl_xor(d1, off);
        }
        const float pm = fmaxf(d0, d1);
        if (__builtin_expect(pm > m + 8.f, 0)) {
            const float sc = __expf(m - pm);
            m = pm;
            denom *= sc;
#pragma unroll
            for (int v = 0; v < 8; ++v) acc[v] *= sc;
        }
        const float w0 = __expf(d0 - m), w1 = __expf(d1 - m);
        denom += w0 + w1;
        const h2 wA = {(_Float16)w0, (_Float16)w1};
#pragma unroll
        for (int v = 0; v < 8; ++v) {
            h2 pA = {x0[v], x1[v]};
            acc[v] = fdot2h(wA, pA, acc[v]);
        }
    }
    if (p < p1) {   // single tail
        const int s0 = ssrc[p];
        const h8 x0 = *(const h8*)(xl + (size_t)s0 * C + cb);
        float d0 = 0.f;
#pragma unroll
        for (int i = 0; i < 4; ++i) {
            h2 xa = {x0[2 * i], x0[2 * i + 1]};
            h2 e0 = xa + r2[i];
            d0 = fdot2h(a6[i], e0, fdot2h(a4[i], habs2(e0), d0));
        }
#pragma unroll
        for (int off = LPG >> 1; off; off >>= 1) d0 += __shfl_xor(d0, off);
        if (d0 > m + 8.f) {
            const float sc = __expf(m - d0);
            m = d0;
            denom *= sc;
#pragma unroll
            for (int v = 0; v < 8; ++v) acc[v] *= sc;
        }
        const float w0 = __expf(d0 - m);
        denom += w0;
        const h2 wA = {(_Float16)w0, (_Float16)0.f};
#pragma unroll
        for (int v = 0; v < 8; ++v) {
            h2 pA = {x0[v], x0[v]};
            acc[v] = fdot2h(wA, pA, acc[v]);
        }
    }

    // merge the two half-group states (partner = lane ^ LPG in the wave)
    {
        const float mo = __shfl_xor(m, LPG);
        const float nm = fmaxf(m, mo);
        const float sc = __expf(m - nm);   // empty half: exp(-inf)=0
        denom *= sc;
        denom += __shfl_xor(denom, LPG);
#pragma unroll
        for (int v = 0; v < 8; ++v) {
            acc[v] *= sc;
            acc[v] += __shfl_xor(acc[v], LPG);
        }
        m = nm;
    }
    if (half) return;   // half 0 writes the output

    const float inv = 1.f / (denom + 1e-16f);
    if constexpr (sizeof(OUT_T) == 2) {
        h8 o;
#pragma unroll
        for (int v = 0; v < 8; ++v)
            o[v] = (_Float16)fmaxf(fmaf(acc[v], inv, bias[cb + v]), 0.f);
        *(h8*)&out[(size_t)node * C + cb] = o;
    } else {
        float4 o0, o1;
        o0.x = fmaxf(fmaf(acc[0], inv, bias[cb + 0]), 0.f);
        o0.y = fmaxf(fmaf(acc[1], inv, bias[cb + 1]), 0.f);
        o0.z = fmaxf(fmaf(acc[2], inv, bias[cb + 2]), 0.f);
        o0.w = fmaxf(fmaf(acc[3], inv, bias[cb + 3]), 0.f);
        o1.x = fmaxf(fmaf(acc[4], inv, bias[cb + 4]), 0.f);
        o1.y = fmaxf(fmaf(acc[5], inv, bias[cb + 5]), 0.f);
        o1.z = fmaxf(fmaf(acc[6], inv, bias[cb + 6]), 0.f);
        o1.w = fmaxf(fmaf(acc[7], inv, bias[cb + 7]), 0.f);
        *(float4*)&out[(size_t)node * C + cb] = o0;
        *(float4*)&out[(size_t)node * C + cb + 4] = o1;
    }
}

// ---------------------------------------------------------------------------
extern "C" void kernel_launch(void* const* d_in, const int* in_sizes, int n_in,
                              void* d_out, int out_size, void* d_ws, size_t ws_size,
                              hipStream_t stream)
{
    const float* x    = (const float*)d_in[0];
    const int*   ei   = (const int*)d_in[1];
    const float* Wl1  = (const float*)d_in[2];
    const float* Wr1  = (const float*)d_in[3];
    const float* att1 = (const float*)d_in[4];
    const float* b1   = (const float*)d_in[5];
    const float* Wl2  = (const float*)d_in[6];
    const float* Wr2  = (const float*)d_in[7];
    const float* att2 = (const float*)d_in[8];
    const float* b2   = (const float*)d_in[9];
    float* out = (float*)d_out;

    const int* e_src = ei;
    const int* e_dst = ei + E_EDGES;

    char* ws = (char*)d_ws;
    _Float16* xl = (_Float16*)(ws + 0);            // 12.8 MB
    _Float16* xr = (_Float16*)(ws + 25600000);     // 12.8 MB
    _Float16* h  = (_Float16*)(ws + 51200000);     // 12.8 MB (after sort scratch done)
    unsigned short* sorted_src = (unsigned short*)(ws + 76800000);  // 3.3 MB
    int* offs   = (int*)(ws + 83400192);
    int* bbase  = (int*)(ws + 83600384);
    int* bcount = (int*)(ws + 83602432);
    int* done   = (int*)(ws + 83703808);
    // sort scratch aliases h region: fully consumed before h is written
    unsigned int* bucket_data = (unsigned int*)(ws + 51200000);  // 6.6 MB
    int* counts = (int*)(ws + 58000000);           // NT*NB*4 = 316 KB
    int* rstart = (int*)(ws + 58400000);           // NB*NT*4 = 316 KB
    _Float16* hl = xl;   // layer-2 transforms reuse xl/xr space
    _Float16* hr = xr;

    // 1. fused: layer-1 transforms + edge tile histogram (+ done reset)
    fused_t1_hist<<<2 * GB1 + NT, 256, 0, stream>>>(
        x, Wl1, Wr1, xl, xr, e_src, e_dst, counts, done);

    // 2. per-bucket tile-offset scan, folded bucket base scan
    row_scan_base<<<NB, 512, 0, stream>>>(counts, rstart, bcount, bbase, done);

    // 3. tiles -> bucket-grouped entries (hist from counts, no re-hist)
    tile_scatter<<<NT, 512, 0, stream>>>(
        e_src, e_dst, counts, rstart, bbase, bucket_data);

    // 4. in-bucket sort -> offs, sorted_src (coarse src order within lists)
    bucket_sort<<<NB, 1024, 0, stream>>>(bucket_data, bbase, offs, sorted_src);

    // 5. layer-1 fused edge pass (split-pair, 32 lanes/node)
    gat_edge_pass<128, 16, _Float16><<<(N_NODES * 32 + 255) / 256, 256, 0, stream>>>(
        xl, xr, att1, b1, offs, sorted_src, h);

    // 6. layer-2 node transforms (fp16 in/out)
    transform2_gemm<<<(N_NODES + 127) / 128, 256, 0, stream>>>(
        h, Wl2, Wr2, hl, hr);

    // 7. layer-2 fused edge pass (split-pair, 8 lanes/node), fp32 out
    gat_edge_pass<32, 4, float><<<(N_NODES * 8 + 255) / 256, 256, 0, stream>>>(
        hl, hr, att2, b2, offs, sorted_src, out);
}

// Round 15
// 162.164 us; speedup vs baseline: 1.0853x; 1.0853x over previous
//
#include <hip/hip_runtime.h>
#include <hip/hip_bf16.h>

#define N_NODES 50000
#define E_EDGES 1600000
#define E_TOT   (E_EDGES + N_NODES)   // 1,650,000
#define NEG_SLOPE 0.2f

#define NB       196                  // buckets of 256 dst nodes
#define S1_TILE  4096
#define NT       ((E_TOT + S1_TILE - 1) / S1_TILE)   // 403 tiles
#define S2_CAP   10240
#define GB1      ((N_NODES + 127) / 128)             // 391 gemm tiles

typedef _Float16 h2 __attribute__((ext_vector_type(2)));
typedef _Float16 h4 __attribute__((ext_vector_type(4)));
typedef _Float16 h8 __attribute__((ext_vector_type(8)));

__device__ __forceinline__ float fdot2h(h2 a, h2 b, float c)
{
#if __has_builtin(__builtin_amdgcn_fdot2)
    return __builtin_amdgcn_fdot2(a, b, c, false);
#else
    return c + (float)a[0] * (float)b[0] + (float)a[1] * (float)b[1];
#endif
}

__device__ __forceinline__ h2 habs2(h2 e)
{
    unsigned int u = __builtin_bit_cast(unsigned int, e) & 0x7FFF7FFFu;
    return __builtin_bit_cast(h2, u);
}

// inclusive wave scan (64 lanes)
__device__ __forceinline__ int wave_iscan(int v, int lane)
{
#pragma unroll
    for (int off = 1; off < 64; off <<= 1) {
        int u = __shfl_up(v, off);
        if (lane >= off) v += u;
    }
    return v;
}

// ---------------------------------------------------------------------------
// Fused: layer-1 transform (blocks 0..2*GB1) + tile_hist (blocks 2*GB1..).
// ---------------------------------------------------------------------------
__global__ __launch_bounds__(256) void fused_t1_hist(
    const float* __restrict__ x,
    const float* __restrict__ Wl, const float* __restrict__ Wr,
    _Float16* __restrict__ xl, _Float16* __restrict__ xr,
    const int* __restrict__ src, const int* __restrict__ dst,
    int* __restrict__ counts, int* __restrict__ done)
{
    __shared__ h2 xs2[16][128];
    __shared__ h2 ws2[16][128];
    __shared__ int hh[NB];
    const int t = threadIdx.x;

    if (blockIdx.x >= 2 * GB1) {
        // ---- tile_hist part ----
        const int tile = blockIdx.x - 2 * GB1;
        if (tile == 0 && t == 0) *done = 0;    // reset for row_scan_base
        const int base = tile * S1_TILE;
        for (int i = t; i < NB; i += 256) hh[i] = 0;
        __syncthreads();
#pragma unroll
        for (int k = 0; k < S1_TILE / 256; ++k) {
            const int i = base + k * 256 + t;
            if (i < E_TOT) {
                const int d = (i < E_EDGES) ? dst[i] : (i - E_EDGES);
                atomicAdd(&hh[d >> 8], 1);
            }
        }
        __syncthreads();
        for (int b = t; b < NB; b += 256)
            counts[tile * NB + b] = hh[b];
        return;
    }

    // ---- transform1 part ----
    const int n0 = (blockIdx.x >> 1) * 128;
    const float* __restrict__ W = (blockIdx.x & 1) ? Wr : Wl;
    _Float16* __restrict__ Y = (blockIdx.x & 1) ? xr : xl;
    const int tc = t & 15;
    const int tn = t >> 4;

    float acc[2][4][2][4];
#pragma unroll
    for (int nh = 0; nh < 2; ++nh)
#pragma unroll
        for (int i = 0; i < 4; ++i)
#pragma unroll
            for (int ch = 0; ch < 2; ++ch)
#pragma unroll
                for (int j = 0; j < 4; ++j) acc[nh][i][ch][j] = 0.f;

    for (int k0 = 0; k0 < 128; k0 += 32) {
        {
            const int node = t >> 1;
            const int kh = (t & 1) * 16;
            const int gn = n0 + node;
#pragma unroll
            for (int q = 0; q < 4; ++q) {
                float4 v = make_float4(0.f, 0.f, 0.f, 0.f);
                if (gn < N_NODES)
                    v = *(const float4*)&x[(size_t)gn * 128 + k0 + kh + q * 4];
                h2 p0 = {(_Float16)v.x, (_Float16)v.y};
                h2 p1 = {(_Float16)v.z, (_Float16)v.w};
                xs2[kh / 2 + q * 2 + 0][node] = p0;
                xs2[kh / 2 + q * 2 + 1][node] = p1;
            }
        }
        {
            const int c = t & 127;
            const int kq = (t >> 7) * 16;
#pragma unroll
            for (int ii = 0; ii < 8; ++ii) {
                h2 pw = {(_Float16)W[(size_t)(k0 + kq + 2 * ii) * 128 + c],
                         (_Float16)W[(size_t)(k0 + kq + 2 * ii + 1) * 128 + c]};
                ws2[kq / 2 + ii][c] = pw;
            }
        }
        __syncthreads();
#pragma unroll 4
        for (int k2 = 0; k2 < 16; ++k2) {
            h2 a0[4], a1[4], b0[4], b1[4];
#pragma unroll
            for (int j = 0; j < 4; ++j) {
                a0[j] = xs2[k2][tn * 4 + j];
                a1[j] = xs2[k2][64 + tn * 4 + j];
                b0[j] = ws2[k2][tc * 4 + j];
                b1[j] = ws2[k2][64 + tc * 4 + j];
            }
#pragma unroll
            for (int i = 0; i < 4; ++i)
#pragma unroll
                for (int j = 0; j < 4; ++j) {
                    acc[0][i][0][j] = fdot2h(a0[i], b0[j], acc[0][i][0][j]);
                    acc[0][i][1][j] = fdot2h(a0[i], b1[j], acc[0][i][1][j]);
                    acc[1][i][0][j] = fdot2h(a1[i], b0[j], acc[1][i][0][j]);
                    acc[1][i][1][j] = fdot2h(a1[i], b1[j], acc[1][i][1][j]);
                }
        }
        __syncthreads();
    }
#pragma unroll
    for (int nh = 0; nh < 2; ++nh)
#pragma unroll
        for (int i = 0; i < 4; ++i) {
            const int node = n0 + nh * 64 + tn * 4 + i;
            if (node < N_NODES) {
#pragma unroll
                for (int ch = 0; ch < 2; ++ch) {
                    h4 v;
                    v[0] = (_Float16)acc[nh][i][ch][0];
                    v[1] = (_Float16)acc[nh][i][ch][1];
                    v[2] = (_Float16)acc[nh][i][ch][2];
                    v[3] = (_Float16)acc[nh][i][ch][3];
                    *(h4*)&Y[(size_t)node * 128 + ch * 64 + tc * 4] = v;
                }
            }
        }
}

// ---------------------------------------------------------------------------
// Layer-2 transform: [N,128] fp16 @ (Wl2|Wr2)[128,32] -> hl, hr fp16.
// ---------------------------------------------------------------------------
__global__ __launch_bounds__(256) void transform2_gemm(
    const _Float16* __restrict__ h,
    const float* __restrict__ Wl, const float* __restrict__ Wr,
    _Float16* __restrict__ hl, _Float16* __restrict__ hr)
{
    __shared__ h2 xs2[16][128];
    __shared__ h2 ws2[16][64];
    const int n0 = blockIdx.x * 128;
    const int t = threadIdx.x;
    const int tc = t & 15;
    const int tn = t >> 4;

    float acc[2][4][4];
#pragma unroll
    for (int nh = 0; nh < 2; ++nh)
#pragma unroll
        for (int i = 0; i < 4; ++i)
#pragma unroll
            for (int j = 0; j < 4; ++j) acc[nh][i][j] = 0.f;

    for (int k0 = 0; k0 < 128; k0 += 32) {
        {
            const int node = t >> 1;
            const int kh = (t & 1) * 16;
            const int gn = n0 + node;
            h8 v0 = {}, v1 = {};
            if (gn < N_NODES) {
                v0 = *(const h8*)&h[(size_t)gn * 128 + k0 + kh];
                v1 = *(const h8*)&h[(size_t)gn * 128 + k0 + kh + 8];
            }
#pragma unroll
            for (int q = 0; q < 4; ++q) {
                h2 p0 = {v0[2 * q], v0[2 * q + 1]};
                h2 p1 = {v1[2 * q], v1[2 * q + 1]};
                xs2[kh / 2 + q][node] = p0;
                xs2[kh / 2 + 4 + q][node] = p1;
            }
        }
        {
            const int c = t & 63;
            const int kq = (t >> 6) * 8;
            const float* __restrict__ Wm = (c < 32) ? Wl : Wr;
            const int wc = c & 31;
#pragma unroll
            for (int ii = 0; ii < 4; ++ii) {
                h2 pw = {(_Float16)Wm[(size_t)(k0 + kq + 2 * ii) * 32 + wc],
                         (_Float16)Wm[(size_t)(k0 + kq + 2 * ii + 1) * 32 + wc]};
                ws2[kq / 2 + ii][c] = pw;
            }
        }
        __syncthreads();
#pragma unroll 4
        for (int k2 = 0; k2 < 16; ++k2) {
            h2 a0[4], a1[4], b[4];
#pragma unroll
            for (int j = 0; j < 4; ++j) {
                a0[j] = xs2[k2][tn * 4 + j];
                a1[j] = xs2[k2][64 + tn * 4 + j];
                b[j] = ws2[k2][tc * 4 + j];
            }
#pragma unroll
            for (int i = 0; i < 4; ++i)
#pragma unroll
                for (int j = 0; j < 4; ++j) {
                    acc[0][i][j] = fdot2h(a0[i], b[j], acc[0][i][j]);
                    acc[1][i][j] = fdot2h(a1[i], b[j], acc[1][i][j]);
                }
        }
        __syncthreads();
    }
    _Float16* __restrict__ Y = (tc < 8) ? hl : hr;
    const int col = (tc < 8) ? tc * 4 : tc * 4 - 32;
#pragma unroll
    for (int nh = 0; nh < 2; ++nh)
#pragma unroll
        for (int i = 0; i < 4; ++i) {
            const int node = n0 + nh * 64 + tn * 4 + i;
            if (node < N_NODES) {
                h4 v;
                v[0] = (_Float16)acc[nh][i][0];
                v[1] = (_Float16)acc[nh][i][1];
                v[2] = (_Float16)acc[nh][i][2];
                v[3] = (_Float16)acc[nh][i][3];
                *(h4*)&Y[(size_t)node * 32 + col] = v;
            }
        }
}

// ---------------------------------------------------------------------------
// row_scan + folded bucket_base (last-block-done pattern).
// ---------------------------------------------------------------------------
__global__ __launch_bounds__(512) void row_scan_base(
    const int* __restrict__ counts, int* __restrict__ rstart,
    int* __restrict__ bcount, int* __restrict__ bbase, int* __restrict__ done)
{
    __shared__ int wsum[8];
    __shared__ int amLast;
    const int b = blockIdx.x;
    const int t = threadIdx.x;
    const int lane = t & 63, wid = t >> 6;
    const int v = (t < NT) ? counts[t * NB + b] : 0;
    int inc = wave_iscan(v, lane);
    if (lane == 63) wsum[wid] = inc;
    __syncthreads();
    if (t == 0) {
        int s = 0;
#pragma unroll
        for (int w = 0; w < 8; ++w) { int u = wsum[w]; wsum[w] = s; s += u; }
    }
    __syncthreads();
    const int excl = inc - v + wsum[wid];
    if (t < NT) rstart[b * NT + t] = excl;
    if (t == 511) {
        bcount[b] = excl;   // v==0 here, excl == row total
        __threadfence();
        const int old = atomicAdd(done, 1);
        amLast = (old == NB - 1) ? 1 : 0;
    }
    __syncthreads();
    if (amLast) {
        __threadfence();    // see all blocks' bcount
        const int v2 = (t < NB) ? bcount[t] : 0;
        int inc2 = wave_iscan(v2, lane);
        if (lane == 63 && wid < 4) wsum[wid] = inc2;
        __syncthreads();
        if (t == 0) {
            int s = 0;
#pragma unroll
            for (int w = 0; w < 4; ++w) { int u = wsum[w]; wsum[w] = s; s += u; }
        }
        __syncthreads();
        if (t < 256) {
            const int excl2 = inc2 - v2 + wsum[wid];
            if (t < NB) bbase[t] = excl2;
            if (t == NB - 1) bbase[NB] = excl2 + v2;   // == E_TOT
        }
    }
}

// tile_scatter: hist comes from the counts row (computed in stage 1).
__global__ __launch_bounds__(512) void tile_scatter(
    const int* __restrict__ src, const int* __restrict__ dst,
    const int* __restrict__ counts,
    const int* __restrict__ rstart, const int* __restrict__ bbase,
    unsigned int* __restrict__ bucket_data)
{
    __shared__ int cur[NB];
    __shared__ int rs[NB];
    __shared__ int wsum[8];
    __shared__ unsigned int srt[S1_TILE];   // 16 KB
    const int t = threadIdx.x;
    const int tile = blockIdx.x;
    const int base = tile * S1_TILE;
    const int tcount = min(S1_TILE, E_TOT - base);

    int eb[S1_TILE / 512];
    unsigned int ee[S1_TILE / 512];
#pragma unroll
    for (int k = 0; k < S1_TILE / 512; ++k) {
        const int i = base + k * 512 + t;
        eb[k] = -1;
        if (i < E_TOT) {
            int s, d;
            if (i < E_EDGES) { s = src[i]; d = dst[i]; }
            else { s = i - E_EDGES; d = s; }     // self loop
            const int b = d >> 8;
            eb[k] = b;
            ee[k] = ((unsigned)b << 24) | ((unsigned)(d & 255) << 16) | (unsigned)s;
        }
    }
    {
        const int lane = t & 63, wid = t >> 6;
        const int v = (t < NB) ? counts[tile * NB + t] : 0;
        int inc = wave_iscan(v, lane);
        if (lane == 63 && wid < 4) wsum[wid] = inc;
        __syncthreads();
        if (t == 0) {
            int s = 0;
#pragma unroll
            for (int w = 0; w < 4; ++w) { int u = wsum[w]; wsum[w] = s; s += u; }
        }
        __syncthreads();
        if (t < NB) {
            const int excl = inc - v + wsum[wid];
            cur[t] = excl;
            rs[t] = bbase[t] + rstart[t * NT + tile] - excl;
        }
    }
    __syncthreads();
#pragma unroll
    for (int k = 0; k < S1_TILE / 512; ++k) {
        if (eb[k] >= 0) {
            const int pos = atomicAdd(&cur[eb[k]], 1);
            srt[pos] = ee[k];
        }
    }
    __syncthreads();
    for (int i = t; i < tcount; i += 512) {
        const unsigned int e = srt[i];
        bucket_data[rs[e >> 24] + i] = e;
    }
}

// Two-pass in-bucket sort (src-coarse then dst-byte), LDS-staged output.
__global__ __launch_bounds__(1024) void bucket_sort(
    const unsigned int* __restrict__ bucket_data,
    const int* __restrict__ bbase,
    int* __restrict__ offs, unsigned short* __restrict__ sorted_src)
{
    __shared__ int hist[256];                   // dst-byte histogram
    __shared__ int hsrc[256];                   // src-high histogram
    __shared__ int cur[256];
    __shared__ int csrc[256];
    __shared__ int wsum[4];
    __shared__ unsigned int srt4[S2_CAP];       // 40 KB
    __shared__ unsigned short srt2[S2_CAP];     // 20 KB
    const int b = blockIdx.x;
    const int t = threadIdx.x;
    const int lo = bbase[b], hi = bbase[b + 1];
    const int c = hi - lo;
    if (t < 256) { hist[t] = 0; hsrc[t] = 0; }
    __syncthreads();
    for (int i = t; i < c; i += 1024) {
        const unsigned int e = bucket_data[lo + i];
        atomicAdd(&hist[(e >> 16) & 255u], 1);
        atomicAdd(&hsrc[(e >> 8) & 255u], 1);
    }
    __syncthreads();
    // scan hsrc -> csrc
    {
        const int lane = t & 63, wid = t >> 6;
        const int v = (t < 256) ? hsrc[t] : 0;
        int inc = wave_iscan(v, lane);
        if (lane == 63 && wid < 4) wsum[wid] = inc;
        __syncthreads();
        if (t == 0) {
            int s = 0;
#pragma unroll
            for (int w = 0; w < 4; ++w) { int u = wsum[w]; wsum[w] = s; s += u; }
        }
        __syncthreads();
        if (t < 256) csrc[t] = inc - v + wsum[wid];
        __syncthreads();
    }
    // scan hist -> cur (+offs)
    {
        const int lane = t & 63, wid = t >> 6;
        const int v = (t < 256) ? hist[t] : 0;
        int inc = wave_iscan(v, lane);
        if (lane == 63 && wid < 4) wsum[wid] = inc;
        __syncthreads();
        if (t == 0) {
            int s = 0;
#pragma unroll
            for (int w = 0; w < 4; ++w) { int u = wsum[w]; wsum[w] = s; s += u; }
        }
        __syncthreads();
        if (t < 256) {
            const int excl = inc - v + wsum[wid];
            cur[t] = excl;
            const int node = b * 256 + t;
            if (node < N_NODES) offs[node] = lo + excl;
        }
    }
    if (b == 0 && t == 0) offs[N_NODES] = E_TOT;
    __syncthreads();
    // pass 1: scatter by src-high into srt4
    for (int i = t; i < c; i += 1024) {
        const unsigned int e = bucket_data[lo + i];
        const int pos = atomicAdd(&csrc[(e >> 8) & 255u], 1);
        srt4[pos] = e;
    }
    __syncthreads();
    // pass 2: scatter by dst-byte (approx stable) into srt2
    for (int i = t; i < c; i += 1024) {
        const unsigned int e = srt4[i];
        const int pos = atomicAdd(&cur[(e >> 16) & 255u], 1);
        srt2[pos] = (unsigned short)(e & 0xFFFFu);
    }
    __syncthreads();
    for (int i = t; i < c; i += 1024)
        sorted_src[lo + i] = srt2[i];           // coalesced 2B stores
}

// ---------------------------------------------------------------------------
// Fused GATv2 edge pass, fp16, quad-unrolled online softmax, SPLIT-PAIR
// (round-13 form: NO prefetch — VGPR must stay at 40 for occupancy).
// ---------------------------------------------------------------------------
template <int C, int LPG, typename OUT_T>
__global__ __launch_bounds__(256) void gat_edge_pass(
    const _Float16* __restrict__ xl, const _Float16* __restrict__ xr,
    const float* __restrict__ att, const float* __restrict__ bias,
    const int* __restrict__ offs, const unsigned short* __restrict__ ssrc,
    OUT_T* __restrict__ out)
{
    constexpr int GPN = 2 * LPG;       // lanes per node (two half-groups)
    static_assert(C == LPG * 8, "8 halves per lane per half-group");
    const int node = (blockIdx.x * 256 + threadIdx.x) / GPN;
    if (node >= N_NODES) return;
    const int half = (threadIdx.x / LPG) & 1;
    const int lane = threadIdx.x % LPG;
    const int cb = lane * 8;

    h2 a6[4], a4[4], r2[4];
    {
        const h8 rv = *(const h8*)(xr + (size_t)node * C + cb);
#pragma unroll
        for (int i = 0; i < 4; ++i) {
            const float av0 = att[cb + 2 * i], av1 = att[cb + 2 * i + 1];
            h2 t6 = {(_Float16)(0.6f * av0), (_Float16)(0.6f * av1)};
            h2 t4 = {(_Float16)(0.4f * av0), (_Float16)(0.4f * av1)};
            a6[i] = t6; a4[i] = t4;
            h2 rr = {rv[2 * i], rv[2 * i + 1]};
            r2[i] = rr;
        }
    }
    float acc[8];
#pragma unroll
    for (int v = 0; v < 8; ++v) acc[v] = 0.f;
    float m = -3.0e38f, denom = 0.f;

    const int p0 = offs[node];
    const int pE = offs[node + 1];
    const int hlen = (pE - p0 + 1) >> 1;
    int p = half ? (p0 + hlen) : p0;
    const int p1 = half ? pE : (p0 + hlen);

    for (; p + 4 <= p1; p += 4) {
        const int s0 = ssrc[p], s1 = ssrc[p + 1];
        const int s2 = ssrc[p + 2], s3 = ssrc[p + 3];
        const h8 x0 = *(const h8*)(xl + (size_t)s0 * C + cb);
        const h8 x1 = *(const h8*)(xl + (size_t)s1 * C + cb);
        const h8 x2 = *(const h8*)(xl + (size_t)s2 * C + cb);
        const h8 x3 = *(const h8*)(xl + (size_t)s3 * C + cb);
        float d0 = 0.f, d1 = 0.f, d2 = 0.f, d3 = 0.f;
#pragma unroll
        for (int i = 0; i < 4; ++i) {
            h2 xa = {x0[2 * i], x0[2 * i + 1]};
            h2 xb = {x1[2 * i], x1[2 * i + 1]};
            h2 xc = {x2[2 * i], x2[2 * i + 1]};
            h2 xd = {x3[2 * i], x3[2 * i + 1]};
            h2 e0 = xa + r2[i], e1 = xb + r2[i];
            h2 e2 = xc + r2[i], e3 = xd + r2[i];
            d0 = fdot2h(a6[i], e0, fdot2h(a4[i], habs2(e0), d0));
            d1 = fdot2h(a6[i], e1, fdot2h(a4[i], habs2(e1), d1));
            d2 = fdot2h(a6[i], e2, fdot2h(a4[i], habs2(e2), d2));
            d3 = fdot2h(a6[i], e3, fdot2h(a4[i], habs2(e3), d3));
        }
#pragma unroll
        for (int off = LPG >> 1; off; off >>= 1) {
            d0 += __shfl_xor(d0, off);
            d1 += __shfl_xor(d1, off);
            d2 += __shfl_xor(d2, off);
            d3 += __shfl_xor(d3, off);
        }
        const float pm = fmaxf(fmaxf(d0, d1), fmaxf(d2, d3));
        if (__builtin_expect(pm > m + 8.f, 0)) {
            const float sc = __expf(m - pm);     // first quad: exp(-inf) = 0
            m = pm;
            denom *= sc;
#pragma unroll
            for (int v = 0; v < 8; ++v) acc[v] *= sc;
        }
        const float w0 = __expf(d0 - m), w1 = __expf(d1 - m);
        const float w2 = __expf(d2 - m), w3 = __expf(d3 - m);
        denom += (w0 + w1) + (w2 + w3);
        const h2 wA = {(_Float16)w0, (_Float16)w1};
        const h2 wB = {(_Float16)w2, (_Float16)w3};
#pragma unroll
        for (int v = 0; v < 8; ++v) {
            h2 pA = {x0[v], x1[v]};
            h2 pB = {x2[v], x3[v]};
            acc[v] = fdot2h(wA, pA, fdot2h(wB, pB, acc[v]));
        }
    }
    for (; p + 2 <= p1; p += 2) {
        const int s0 = ssrc[p], s1 = ssrc[p + 1];
        const h8 x0 = *(const h8*)(xl + (size_t)s0 * C + cb);
        const h8 x1 = *(const h8*)(xl + (size_t)s1 * C + cb);
        float d0 = 0.f, d1 = 0.f;
#pragma unroll
        for (int i = 0; i < 4; ++i) {
            h2 xa = {x0[2 * i], x0[2 * i + 1]};
            h2 xb = {x1[2 * i], x1[2 * i + 1]};
            h2 e0 = xa + r2[i], e1 = xb + r2[i];
            d0 = fdot2h(a6[i], e0, fdot2h(a4[i], habs2(e0), d0));
            d1 = fdot2h(a6[i], e1, fdot2h(a4[i], habs2(e1), d1));
        }
#pragma unroll
        for (int off = LPG >> 1; off; off >>= 1) {
            d0 += __shfl_xor(d0, off);
            d1 += __shfl_xor(d1, off);
        }
        const float pm = fmaxf(d0, d1);
        if (__builtin_expect(pm > m + 8.f, 0)) {
            const float sc = __expf(m - pm);
            m = pm;
            denom *= sc;
#pragma unroll
            for (int v = 0; v < 8; ++v) acc[v] *= sc;
        }
        const float w0 = __expf(d0 - m), w1 = __expf(d1 - m);
        denom += w0 + w1;
        const h2 wA = {(_Float16)w0, (_Float16)w1};
#pragma unroll
        for (int v = 0; v < 8; ++v) {
            h2 pA = {x0[v], x1[v]};
            acc[v] = fdot2h(wA, pA, acc[v]);
        }
    }
    if (p < p1) {   // single tail
        const int s0 = ssrc[p];
        const h8 x0 = *(const h8*)(xl + (size_t)s0 * C + cb);
        float d0 = 0.f;
#pragma unroll
        for (int i = 0; i < 4; ++i) {
            h2 xa = {x0[2 * i], x0[2 * i + 1]};
            h2 e0 = xa + r2[i];
            d0 = fdot2h(a6[i], e0, fdot2h(a4[i], habs2(e0), d0));
        }
#pragma unroll
        for (int off = LPG >> 1; off; off >>= 1) d0 += __shfl_xor(d0, off);
        if (d0 > m + 8.f) {
            const float sc = __expf(m - d0);
            m = d0;
            denom *= sc;
#pragma unroll
            for (int v = 0; v < 8; ++v) acc[v] *= sc;
        }
        const float w0 = __expf(d0 - m);
        denom += w0;
        const h2 wA = {(_Float16)w0, (_Float16)0.f};
#pragma unroll
        for (int v = 0; v < 8; ++v) {
            h2 pA = {x0[v], x0[v]};
            acc[v] = fdot2h(wA, pA, acc[v]);
        }
    }

    // merge the two half-group states (partner = lane ^ LPG in the wave)
    {
        const float mo = __shfl_xor(m, LPG);
        const float nm = fmaxf(m, mo);
        const float sc = __expf(m - nm);   // empty half: exp(-inf)=0
        denom *= sc;
        denom += __shfl_xor(denom, LPG);
#pragma unroll
        for (int v = 0; v < 8; ++v) {
            acc[v] *= sc;
            acc[v] += __shfl_xor(acc[v], LPG);
        }
        m = nm;
    }
    if (half) return;   // half 0 writes the output

    const float inv = 1.f / (denom + 1e-16f);
    if constexpr (sizeof(OUT_T) == 2) {
        h8 o;
#pragma unroll
        for (int v = 0; v < 8; ++v)
            o[v] = (_Float16)fmaxf(fmaf(acc[v], inv, bias[cb + v]), 0.f);
        *(h8*)&out[(size_t)node * C + cb] = o;
    } else {
        float4 o0, o1;
        o0.x = fmaxf(fmaf(acc[0], inv, bias[cb + 0]), 0.f);
        o0.y = fmaxf(fmaf(acc[1], inv, bias[cb + 1]), 0.f);
        o0.z = fmaxf(fmaf(acc[2], inv, bias[cb + 2]), 0.f);
        o0.w = fmaxf(fmaf(acc[3], inv, bias[cb + 3]), 0.f);
        o1.x = fmaxf(fmaf(acc[4], inv, bias[cb + 4]), 0.f);
        o1.y = fmaxf(fmaf(acc[5], inv, bias[cb + 5]), 0.f);
        o1.z = fmaxf(fmaf(acc[6], inv, bias[cb + 6]), 0.f);
        o1.w = fmaxf(fmaf(acc[7], inv, bias[cb + 7]), 0.f);
        *(float4*)&out[(size_t)node * C + cb] = o0;
        *(float4*)&out[(size_t)node * C + cb + 4] = o1;
    }
}

// ---------------------------------------------------------------------------
extern "C" void kernel_launch(void* const* d_in, const int* in_sizes, int n_in,
                              void* d_out, int out_size, void* d_ws, size_t ws_size,
                              hipStream_t stream)
{
    const float* x    = (const float*)d_in[0];
    const int*   ei   = (const int*)d_in[1];
    const float* Wl1  = (const float*)d_in[2];
    const float* Wr1  = (const float*)d_in[3];
    const float* att1 = (const float*)d_in[4];
    const float* b1   = (const float*)d_in[5];
    const float* Wl2  = (const float*)d_in[6];
    const float* Wr2  = (const float*)d_in[7];
    const float* att2 = (const float*)d_in[8];
    const float* b2   = (const float*)d_in[9];
    float* out = (float*)d_out;

    const int* e_src = ei;
    const int* e_dst = ei + E_EDGES;

    char* ws = (char*)d_ws;
    _Float16* xl = (_Float16*)(ws + 0);            // 12.8 MB
    _Float16* xr = (_Float16*)(ws + 25600000);     // 12.8 MB
    _Float16* h  = (_Float16*)(ws + 51200000);     // 12.8 MB (after sort scratch done)
    unsigned short* sorted_src = (unsigned short*)(ws + 76800000);  // 3.3 MB
    int* offs   = (int*)(ws + 83400192);
    int* bbase  = (int*)(ws + 83600384);
    int* bcount = (int*)(ws + 83602432);
    int* done   = (int*)(ws + 83703808);
    // sort scratch aliases h region: fully consumed before h is written
    unsigned int* bucket_data = (unsigned int*)(ws + 51200000);  // 6.6 MB
    int* counts = (int*)(ws + 58000000);           // NT*NB*4 = 316 KB
    int* rstart = (int*)(ws + 58400000);           // NB*NT*4 = 316 KB
    _Float16* hl = xl;   // layer-2 transforms reuse xl/xr space
    _Float16* hr = xr;

    // 1. fused: layer-1 transforms + edge tile histogram (+ done reset)
    fused_t1_hist<<<2 * GB1 + NT, 256, 0, stream>>>(
        x, Wl1, Wr1, xl, xr, e_src, e_dst, counts, done);

    // 2. per-bucket tile-offset scan, folded bucket base scan
    row_scan_base<<<NB, 512, 0, stream>>>(counts, rstart, bcount, bbase, done);

    // 3. tiles -> bucket-grouped entries (hist from counts, no re-hist)
    tile_scatter<<<NT, 512, 0, stream>>>(
        e_src, e_dst, counts, rstart, bbase, bucket_data);

    // 4. in-bucket sort -> offs, sorted_src (coarse src order within lists)
    bucket_sort<<<NB, 1024, 0, stream>>>(bucket_data, bbase, offs, sorted_src);

    // 5. layer-1 fused edge pass (split-pair, 32 lanes/node)
    gat_edge_pass<128, 16, _Float16><<<(N_NODES * 32 + 255) / 256, 256, 0, stream>>>(
        xl, xr, att1, b1, offs, sorted_src, h);

    // 6. layer-2 node transforms (fp16 in/out)
    transform2_gemm<<<(N_NODES + 127) / 128, 256, 0, stream>>>(
        h, Wl2, Wr2, hl, hr);

    // 7. layer-2 fused edge pass (split-pair, 8 lanes/node), fp32 out
    gat_edge_pass<32, 4, float><<<(N_NODES * 8 + 255) / 256, 256, 0, stream>>>(
        hl, hr, att2, b2, offs, sorted_src, out);
}